// Round 20
// baseline (187.493 us; speedup 1.0000x reference)
//
#include <hip/hip_runtime.h>
#include <math.h>

#define S_LEN 2048
#define DMODEL 1024
#define NH 16
#define DEPTH 64
#define BATCH 2
#define MTOT (BATCH * S_LEN) // 4096

typedef __attribute__((ext_vector_type(8))) short short8;
typedef __attribute__((ext_vector_type(4))) short short4v;
typedef __attribute__((ext_vector_type(4))) float floatx4;

typedef const __attribute__((address_space(1))) unsigned gas_u32;
typedef __attribute__((address_space(3))) unsigned las_u32;

__device__ __forceinline__ short f2bf(float f) {
    union { float f; unsigned u; } v; v.f = f;
    unsigned r = v.u + 0x7fffu + ((v.u >> 16) & 1u);
    return (short)(r >> 16);
}

// Pack two fp32 -> two bf16 in one dword, round-half-up (+0x8000, truncate),
// paired via one v_perm_b32. Valid for finite non-NaN inputs.
__device__ __forceinline__ unsigned packbf2(float lo, float hi) {
    union { float f; unsigned u; } a, b;
    a.f = lo; b.f = hi;
    return __builtin_amdgcn_perm(b.u + 0x8000u, a.u + 0x8000u, 0x07060302u);
}

__device__ __forceinline__ floatx4 mfma16(short8 a, short8 b, floatx4 c) {
    return __builtin_amdgcn_mfma_f32_16x16x32_bf16(a, b, c, 0, 0, 0);
}

// K=16 bf16 MFMA: A/B are 4 bf16 per lane (2 VGPRs). A: row=lane&15, k=(lane>>4)*4+e.
#if __has_builtin(__builtin_amdgcn_mfma_f32_16x16x16bf16_1k)
__device__ __forceinline__ floatx4 mfma16k16(short4v a, short4v b, floatx4 c) {
    return __builtin_amdgcn_mfma_f32_16x16x16bf16_1k(a, b, c, 0, 0, 0);
}
#else
__device__ __forceinline__ floatx4 mfma16k16(short4v a, short4v b, floatx4 c) {
    asm volatile("v_mfma_f32_16x16x16_bf16 %0, %1, %2, %0\n\ts_nop 7\n\ts_nop 7"
                 : "+v"(c) : "v"(a), "v"(b));
    return c;
}
#endif

// ---------------- fused prologue: x conversion + weight transpose (concurrent) ----------------
__global__ __launch_bounds__(256) void prep_kernel(const float* __restrict__ x,
                                                   short* __restrict__ xb,
                                                   const float* __restrict__ w0, const float* __restrict__ w1,
                                                   const float* __restrict__ w2, const float* __restrict__ w3,
                                                   short* __restrict__ o0, short* __restrict__ o1,
                                                   short* __restrict__ o2, short* __restrict__ o3) {
    const int bid = blockIdx.x;
    const int tid = threadIdx.x;
    if (bid < 4096) {
        int i = (bid * 256 + tid) * 4;
        float4 v = *(const float4*)(x + i);
        short4v o;
        o.x = f2bf(v.x); o.y = f2bf(v.y); o.z = f2bf(v.z); o.w = f2bf(v.w);
        *(short4v*)(xb + i) = o;
        return;
    }
    const int b2 = bid - 4096;
    const int z = b2 >> 10;            // 0..3 which weight
    const int rem = b2 & 1023;
    const int bx = rem & 31, by = rem >> 5;
    const float* src; short* dst;
    switch (z) {
        case 0: src = w0; dst = o0; break;
        case 1: src = w1; dst = o1; break;
        case 2: src = w2; dst = o2; break;
        default: src = w3; dst = o3; break;
    }
    __shared__ float tile[32][33];
    const int tx = tid & 31, ty = tid >> 5;   // 32 x 8
    int c = bx * 32 + tx;
    int r0 = by * 32;
#pragma unroll
    for (int i = 0; i < 4; i++)
        tile[ty + i * 8][tx] = src[(size_t)(r0 + ty + i * 8) * DMODEL + c];
    __syncthreads();
    int co = by * 32 + tx;
    int ro = bx * 32;
#pragma unroll
    for (int i = 0; i < 4; i++)
        dst[(size_t)(ro + ty + i * 8) * DMODEL + co] = f2bf(tile[tx][ty + i * 8]);
}

// ---------------- GEMM v6: A in LDS dbuf (R18-proven), B in register prefetch ----------------
// LDS halves to 32KB -> all 768 blocks resident (3/CU, was 2/CU + 256-block tail).
// B fragments (8 x short8 / wave) load global->reg one K-step ahead (T14); B is
// L2-hot because the 4 m-sub blocks of an XCD share it (R17 XCD decode).
__device__ __forceinline__ void stage_tile(const short* __restrict__ src, int row0, int k0,
                                           short* dstLds, int tid) {
#pragma unroll
    for (int s = 0; s < 4; s++) {
        const int p = s * 4096 + tid * 16;           // linear LDS byte position
        const int q = p ^ (((p >> 7) & 7) << 4);     // inverse-swizzled tile byte
        const char* srcp = (const char*)src + (size_t)(row0 + (q >> 7)) * (DMODEL * 2)
                         + k0 * 2 + (q & 127);
        __builtin_amdgcn_global_load_lds((gas_u32*)srcp,
                                         (las_u32*)((char*)dstLds + p), 16, 0, 0);
    }
}

__device__ __forceinline__ void loadB(const short* __restrict__ bbase, int ks, short8 bf[8]) {
#pragma unroll
    for (int j = 0; j < 4; j++)
#pragma unroll
        for (int kk = 0; kk < 2; kk++)
            bf[j * 2 + kk] = *(const short8*)(bbase + (size_t)(j * 16) * DMODEL + ks * 64 + kk * 32);
}

__device__ __forceinline__ void mfma_step(const char* Ac, const int aoffs[4][2],
                                          const short8 bf[8], floatx4 acc[4][4]) {
#pragma unroll
    for (int kk = 0; kk < 2; kk++) {
        short8 af[4];
#pragma unroll
        for (int i = 0; i < 4; i++) af[i] = *(const short8*)(Ac + aoffs[i][kk]);
#pragma unroll
        for (int i = 0; i < 4; i++)
#pragma unroll
            for (int j = 0; j < 4; j++)
                acc[i][j] = mfma16(af[i], bf[j * 2 + kk], acc[i][j]);
    }
}

__device__ __forceinline__ void gemm_core(const short* __restrict__ A,
                                          const short* __restrict__ Bt,
                                          int m0, int n0,
                                          short* Ab0, short* Ab1,
                                          floatx4 acc[4][4]) {
    const int tid = threadIdx.x;
    const int lane = tid & 63;
    const int w = tid >> 6;
    const int wr = w >> 1, wc = w & 1;
    const int l15 = lane & 15, lhi = lane >> 4;
    const int swz = (l15 & 7) << 4;

    int aoffs[4][2];
#pragma unroll
    for (int i = 0; i < 4; i++) {
        int row = wr * 64 + i * 16 + l15;
#pragma unroll
        for (int kk = 0; kk < 2; kk++)
            aoffs[i][kk] = ((row * 128) + kk * 64 + lhi * 16) ^ swz;
    }
    const short* bbase = Bt + (size_t)(n0 + wc * 64 + l15) * DMODEL + lhi * 8;

    short8 b0[8], b1[8];
    stage_tile(A, m0, 0, Ab0, tid);
    loadB(bbase, 0, b0);
    asm volatile("s_waitcnt vmcnt(0)" ::: "memory");
    __syncthreads();

    for (int ks = 0; ks < 16; ks += 2) {
        // even step: compute (Ab0, b0); prefetch ks+1 into (Ab1, b1)
        if (ks + 1 < 16) {
            stage_tile(A, m0, (ks + 1) * 64, Ab1, tid);
            loadB(bbase, ks + 1, b1);
        }
        mfma_step((const char*)Ab0, aoffs, b0, acc);
        asm volatile("s_waitcnt vmcnt(0)" ::: "memory");
        __syncthreads();
        // odd step: compute (Ab1, b1); prefetch ks+2 into (Ab0, b0)
        if (ks + 2 < 16) {
            stage_tile(A, m0, (ks + 2) * 64, Ab0, tid);
            loadB(bbase, ks + 2, b0);
        }
        mfma_step((const char*)Ab1, aoffs, b1, acc);
        asm volatile("s_waitcnt vmcnt(0)" ::: "memory");
        __syncthreads();
    }
}

// ---------------- QKV GEMM: 1D grid 768, XCD-local decode ----------------
__global__ __launch_bounds__(256, 3) void gemm_qkv(const short* __restrict__ A,
                                                   const short* __restrict__ wq, const short* __restrict__ wk,
                                                   const short* __restrict__ wv,
                                                   const float* __restrict__ bq, const float* __restrict__ bk,
                                                   const float* __restrict__ bv,
                                                   short* __restrict__ qh, short* __restrict__ kh,
                                                   short* __restrict__ vt) {
    __shared__ __align__(16) short Ab[2][8192];
    // decode: xcd(3b) | msub(2b) | n(3b) | mode(2b)
    const int bid = blockIdx.x;
    const int xcd = bid & 7;
    const int slot = bid >> 3;        // 0..95
    const int msub = slot & 3;        // 0..3
    const int c = slot >> 2;          // 0..23
    const int nt = c & 7;             // 0..7
    const int mode = c >> 3;          // 0..2
    const int m0 = (xcd * 4 + msub) * 128;
    const int n0 = nt * 128;

    const short* Bt = (mode == 0) ? wq : (mode == 1) ? wk : wv;
    const float* bias = (mode == 0) ? bq : (mode == 1) ? bk : bv;

    floatx4 acc[4][4];
    floatx4 z = {0.f, 0.f, 0.f, 0.f};
#pragma unroll
    for (int i = 0; i < 4; i++)
#pragma unroll
        for (int j = 0; j < 4; j++) acc[i][j] = z;

    gemm_core(A, Bt, m0, n0, Ab[0], Ab[1], acc);

    const int lane = threadIdx.x & 63;
    const int w = threadIdx.x >> 6;
    const int wr = w >> 1, wc = w & 1;
    const int l15 = lane & 15, lhi = lane >> 4;
    const float qscale = (mode == 0) ? 0.125f : 1.0f;  // fold 1/sqrt(depth) into Q
#pragma unroll
    for (int i = 0; i < 4; i++) {
#pragma unroll
        for (int j = 0; j < 4; j++) {
            int n = n0 + wc * 64 + j * 16 + l15;
            float bv_ = bias[n];
            int h = n >> 6, d = n & 63;
            int mbase = m0 + wr * 64 + i * 16 + (lhi << 2);
#pragma unroll
            for (int r = 0; r < 4; r++) {
                int m = mbase + r;
                int b = m >> 11, s = m & 2047;
                short val = f2bf((acc[i][j][r] + bv_) * qscale);
                if (mode == 0)
                    qh[((size_t)(b * NH + h) * S_LEN + s) * DEPTH + d] = val;
                else if (mode == 1)
                    kh[((size_t)(b * NH + h) * S_LEN + s) * DEPTH + d] = val;
                else
                    vt[((size_t)(b * NH + h) * DEPTH + d) * S_LEN + s] = val;
            }
        }
    }
}

// ---------------- output projection GEMM: 1D grid 256, XCD-local decode ----------------
__global__ __launch_bounds__(256, 3) void gemm_out(const short* __restrict__ A,
                                                   const short* __restrict__ Bt,
                                                   const float* __restrict__ bias,
                                                   float* __restrict__ out) {
    __shared__ __align__(16) short Ab[2][8192];
    const int bid = blockIdx.x;
    const int xcd = bid & 7;
    const int slot = bid >> 3;        // 0..31
    const int msub = slot & 3;
    const int nt = slot >> 2;         // 0..7
    const int m0 = (xcd * 4 + msub) * 128;
    const int n0 = nt * 128;

    floatx4 acc[4][4];
    floatx4 z = {0.f, 0.f, 0.f, 0.f};
#pragma unroll
    for (int i = 0; i < 4; i++)
#pragma unroll
        for (int j = 0; j < 4; j++) acc[i][j] = z;

    gemm_core(A, Bt, m0, n0, Ab[0], Ab[1], acc);

    const int lane = threadIdx.x & 63;
    const int w = threadIdx.x >> 6;
    const int wr = w >> 1, wc = w & 1;
    const int l15 = lane & 15, lhi = lane >> 4;
#pragma unroll
    for (int i = 0; i < 4; i++) {
#pragma unroll
        for (int j = 0; j < 4; j++) {
            int n = n0 + wc * 64 + j * 16 + l15;
            float bv_ = bias[n];
            int mbase = m0 + wr * 64 + i * 16 + (lhi << 2);
#pragma unroll
            for (int r = 0; r < 4; r++) {
                int m = mbase + r;
                out[(size_t)m * DMODEL + n] = acc[i][j][r] + bv_;
            }
        }
    }
}

// ---------------- flash attention (R18-proven) + T5 setprio on MFMA clusters ----------------
__constant__ int YCHUNK[16] = {15, 13, 11, 9, 7, 5, 3, 1, 0, 2, 4, 6, 8, 10, 12, 14};

__device__ __forceinline__ void stage_kv(const short* __restrict__ kb_j0,  // kb + j0*DEPTH
                                         const short* __restrict__ vb, int j0,
                                         short* kt, short* vt_, int wid, int lane) {
#pragma unroll
    for (int s = 0; s < 2; s++) {
        const int seg = (s * 4 + wid) * 1024;        // byte segment of the 8KB tile
        const int p = seg + lane * 16;               // linear LDS byte position
        const int q = p ^ (((p >> 7) & 7) << 4);     // inverse-swizzled source offset
        __builtin_amdgcn_global_load_lds((gas_u32*)((const char*)kb_j0 + q),
                                         (las_u32*)((char*)kt + seg), 16, 0, 0);
        const char* vsrc = (const char*)vb + (size_t)(q >> 7) * (S_LEN * 2) + j0 * 2 + (q & 127);
        __builtin_amdgcn_global_load_lds((gas_u32*)vsrc,
                                         (las_u32*)((char*)vt_ + seg), 16, 0, 0);
    }
}

__global__ __launch_bounds__(256, 2) void attn_kernel(const short* __restrict__ qh,
                                                      const short* __restrict__ kh,
                                                      const short* __restrict__ vt,
                                                      const float* __restrict__ pm,
                                                      short* __restrict__ ao) {
    __shared__ short kbuf[2][4096];
    __shared__ short vbuf[2][4096];
    const int lane = threadIdx.x & 63;
    const int wid = threadIdx.x >> 6;  // 0..3
    const int bh = blockIdx.x;         // bh fastest -> same-head blocks share an XCD
    const int chunk = YCHUNK[blockIdx.y];  // complementary pairing across y and y+8
    const int b = bh >> 4, h = bh & 15;
    const short* qbp = qh + (size_t)bh * S_LEN * DEPTH;
    const short* kb = kh + (size_t)bh * S_LEN * DEPTH;
    const short* vb = vt + (size_t)bh * DEPTH * S_LEN;
    const float* pmb = pm + b * S_LEN;
    const int l15 = lane & 15, lhi = lane >> 4;
    const int swz = (l15 & 7) << 4;

    const int qwb = chunk * 128 + wid * 32;

    short8 qf[2][2];
#pragma unroll
    for (int qg = 0; qg < 2; qg++)
#pragma unroll
        for (int c = 0; c < 2; c++)
            qf[qg][c] = *(const short8*)(qbp + (size_t)(qwb + qg * 16 + l15) * DEPTH + c * 32 + lhi * 8);

    float m_r[2] = {-1e30f, -1e30f};
    float l_part[2] = {0.f, 0.f};
    floatx4 oacc[2][4];
    floatx4 z = {0.f, 0.f, 0.f, 0.f};
#pragma unroll
    for (int qg = 0; qg < 2; qg++)
#pragma unroll
        for (int dt = 0; dt < 4; dt++) oacc[qg][dt] = z;

    const int NT = 2 * chunk + 2;  // key tiles 0 .. chunk*128+64
    stage_kv(kb, vb, 0, kbuf[0], vbuf[0], wid, lane);
    __syncthreads();

    for (int t = 0; t < NT; t++) {
        const int cur = t & 1;
        if (t + 1 < NT)
            stage_kv(kb + (size_t)(t + 1) * 64 * DEPTH, vb, (t + 1) * 64,
                     kbuf[cur ^ 1], vbuf[cur ^ 1], wid, lane);
        const int j0 = t * 64;
        if (j0 <= qwb + 31) {  // wave-uniform: skip fully-masked tiles (barriers still hit)
            const short* kt = kbuf[cur];
            const short* vtile = vbuf[cur];
            short8 kf[4][2];
#pragma unroll
            for (int tt = 0; tt < 4; tt++)
#pragma unroll
                for (int c = 0; c < 2; c++) {
                    int off = (((tt * 16 + l15) * 128) + c * 64 + lhi * 16) ^ swz;
                    kf[tt][c] = *(const short8*)((const char*)kt + off);
                }
            floatx4 sacc[2][4];
#pragma unroll
            for (int qg = 0; qg < 2; qg++)
#pragma unroll
                for (int tt = 0; tt < 4; tt++) sacc[qg][tt] = z;
            __builtin_amdgcn_s_setprio(1);
#pragma unroll
            for (int tt = 0; tt < 4; tt++)
#pragma unroll
                for (int c = 0; c < 2; c++) {
                    sacc[0][tt] = mfma16(kf[tt][c], qf[0][c], sacc[0][tt]);
                    sacc[1][tt] = mfma16(kf[tt][c], qf[1][c], sacc[1][tt]);
                }
            __builtin_amdgcn_s_setprio(0);
            short4v vf[4][4];
#pragma unroll
            for (int tt = 0; tt < 4; tt++)
#pragma unroll
                for (int dt = 0; dt < 4; dt++) {
                    int off = (((dt * 16 + l15) * 128) + tt * 32 + lhi * 8) ^ swz;
                    vf[tt][dt] = *(const short4v*)((const char*)vtile + off);
                }
            float pd[16];
#pragma unroll
            for (int tt = 0; tt < 4; tt++) {
                float4 pmv = *(const float4*)(pmb + j0 + tt * 16 + lhi * 4);
                pd[tt * 4 + 0] = (1.f - pmv.x) * -1e9f;
                pd[tt * 4 + 1] = (1.f - pmv.y) * -1e9f;
                pd[tt * 4 + 2] = (1.f - pmv.z) * -1e9f;
                pd[tt * 4 + 3] = (1.f - pmv.w) * -1e9f;
            }
#pragma unroll
            for (int qg = 0; qg < 2; qg++) {
                const int q = qwb + qg * 16 + l15;
                const bool domask = (j0 + 63 > qwb + qg * 16);
                float mx = -1e30f;
#pragma unroll
                for (int tt = 0; tt < 4; tt++)
#pragma unroll
                    for (int r = 0; r < 4; r++) {
                        float v = sacc[qg][tt][r] + pd[tt * 4 + r];
                        if (domask) {
                            int key = j0 + tt * 16 + lhi * 4 + r;
                            v = (key > q) ? -1e30f : v;
                        }
                        sacc[qg][tt][r] = v;
                        mx = fmaxf(mx, v);
                    }
                // T13 defer-max: rescale only when the row max materially grows.
                if (!__all(mx <= m_r[qg] + 12.0f)) {
                    mx = fmaxf(mx, __shfl_xor(mx, 16, 64));
                    mx = fmaxf(mx, __shfl_xor(mx, 32, 64));
                    float mnew = fmaxf(m_r[qg], mx);
                    float sf = __expf(m_r[qg] - mnew);
                    m_r[qg] = mnew;
                    l_part[qg] *= sf;
#pragma unroll
                    for (int r = 0; r < 4; r++) {
                        float sfr = __shfl(sf, lhi * 4 + r, 64);
#pragma unroll
                        for (int dt = 0; dt < 4; dt++) oacc[qg][dt][r] *= sfr;
                    }
                }
#pragma unroll
                for (int tt = 0; tt < 4; tt++) {
                    float p0 = __expf(sacc[qg][tt][0] - m_r[qg]);
                    float p1 = __expf(sacc[qg][tt][1] - m_r[qg]);
                    float p2 = __expf(sacc[qg][tt][2] - m_r[qg]);
                    float p3 = __expf(sacc[qg][tt][3] - m_r[qg]);
                    l_part[qg] += (p0 + p1) + (p2 + p3);
                    union { unsigned u[2]; short4v s; } cv;
                    cv.u[0] = packbf2(p0, p1);
                    cv.u[1] = packbf2(p2, p3);
                    __builtin_amdgcn_s_setprio(1);
#pragma unroll
                    for (int dt = 0; dt < 4; dt++)
                        oacc[qg][dt] = mfma16k16(cv.s, vf[tt][dt], oacc[qg][dt]);
                    __builtin_amdgcn_s_setprio(0);
                }
            }
        }
        asm volatile("s_waitcnt vmcnt(0)" ::: "memory");
        __syncthreads();
    }

    // ---- epilogue: reduce per-lane partial sums once ----
#pragma unroll
    for (int qg = 0; qg < 2; qg++) {
        float lsum = l_part[qg];
        lsum += __shfl_xor(lsum, 16, 64);
        lsum += __shfl_xor(lsum, 32, 64);
        float rinv[4];
#pragma unroll
        for (int r = 0; r < 4; r++)
            rinv[r] = 1.0f / __shfl(lsum, lhi * 4 + r, 64);
#pragma unroll
        for (int dt = 0; dt < 4; dt++) {
            int d = dt * 16 + l15;
#pragma unroll
            for (int r = 0; r < 4; r++) {
                int row = qwb + qg * 16 + lhi * 4 + r;
                float o = oacc[qg][dt][r] * rinv[r];
                ao[((size_t)(b * S_LEN) + row) * DMODEL + h * DEPTH + d] = f2bf(o);
            }
        }
    }
}

extern "C" void kernel_launch(void* const* d_in, const int* in_sizes, int n_in,
                              void* d_out, int out_size, void* d_ws, size_t ws_size,
                              hipStream_t stream) {
    const float* x    = (const float*)d_in[0];
    const float* pm   = (const float*)d_in[1];
    const float* wq_w = (const float*)d_in[2];
    const float* wq_b = (const float*)d_in[3];
    const float* wk_w = (const float*)d_in[4];
    const float* wk_b = (const float*)d_in[5];
    const float* wv_w = (const float*)d_in[6];
    const float* wv_b = (const float*)d_in[7];
    const float* wo_w = (const float*)d_in[8];
    const float* wo_b = (const float*)d_in[9];
    float* out = (float*)d_out;

    char* ws = (char*)d_ws;
    const size_t MB = 1024 * 1024;
    short* xb  = (short*)(ws);            // 8 MB : x bf16 (4096x1024)
    short* wqb = (short*)(ws + 8 * MB);   // 2 MB : wq^T bf16
    short* wkb = (short*)(ws + 10 * MB);
    short* wvb = (short*)(ws + 12 * MB);
    short* wob = (short*)(ws + 14 * MB);
    short* qh  = (short*)(ws + 16 * MB);  // 8 MB : Q (B,H,S,depth) bf16, pre-scaled by 0.125
    short* kh  = (short*)(ws + 24 * MB);  // 8 MB : K (B,H,S,depth) bf16
    short* vt  = (short*)(ws + 32 * MB);  // 8 MB : V^T (B,H,depth,S) bf16
    short* ao  = (short*)(ws + 40 * MB);  // 8 MB : attn out (B,S,D) bf16

    prep_kernel<<<8192, 256, 0, stream>>>(x, xb, wq_w, wk_w, wv_w, wo_w,
                                          wqb, wkb, wvb, wob);
    gemm_qkv<<<768, 256, 0, stream>>>(xb, wqb, wkb, wvb, wq_b, wk_b, wv_b,
                                      qh, kh, vt);
    attn_kernel<<<dim3(32, 16), 256, 0, stream>>>(qh, kh, vt, pm, ao);
    gemm_out<<<256, 256, 0, stream>>>(ao, wob, wo_b, out);
}

// Round 21
// 129.576 us; speedup vs baseline: 1.4470x; 1.4470x over previous
//
#include <hip/hip_runtime.h>
#include <math.h>

#define S_LEN 2048
#define DMODEL 1024
#define NH 16
#define DEPTH 64
#define BATCH 2
#define MTOT (BATCH * S_LEN) // 4096

typedef __attribute__((ext_vector_type(8))) short short8;
typedef __attribute__((ext_vector_type(4))) short short4v;
typedef __attribute__((ext_vector_type(4))) float floatx4;

typedef const __attribute__((address_space(1))) unsigned gas_u32;
typedef __attribute__((address_space(3))) unsigned las_u32;

__device__ __forceinline__ short f2bf(float f) {
    union { float f; unsigned u; } v; v.f = f;
    unsigned r = v.u + 0x7fffu + ((v.u >> 16) & 1u);
    return (short)(r >> 16);
}

// Pack two fp32 -> two bf16 in one dword, round-half-up (+0x8000, truncate),
// paired via one v_perm_b32. Valid for finite non-NaN inputs.
__device__ __forceinline__ unsigned packbf2(float lo, float hi) {
    union { float f; unsigned u; } a, b;
    a.f = lo; b.f = hi;
    return __builtin_amdgcn_perm(b.u + 0x8000u, a.u + 0x8000u, 0x07060302u);
}

__device__ __forceinline__ floatx4 mfma16(short8 a, short8 b, floatx4 c) {
    return __builtin_amdgcn_mfma_f32_16x16x32_bf16(a, b, c, 0, 0, 0);
}

// K=16 bf16 MFMA: A/B are 4 bf16 per lane (2 VGPRs). A: row=lane&15, k=(lane>>4)*4+e.
#if __has_builtin(__builtin_amdgcn_mfma_f32_16x16x16bf16_1k)
__device__ __forceinline__ floatx4 mfma16k16(short4v a, short4v b, floatx4 c) {
    return __builtin_amdgcn_mfma_f32_16x16x16bf16_1k(a, b, c, 0, 0, 0);
}
#else
__device__ __forceinline__ floatx4 mfma16k16(short4v a, short4v b, floatx4 c) {
    asm volatile("v_mfma_f32_16x16x16_bf16 %0, %1, %2, %0\n\ts_nop 7\n\ts_nop 7"
                 : "+v"(c) : "v"(a), "v"(b));
    return c;
}
#endif

// ---------------- fused prologue: x conversion + weight transpose (concurrent) ----------------
__global__ __launch_bounds__(256) void prep_kernel(const float* __restrict__ x,
                                                   short* __restrict__ xb,
                                                   const float* __restrict__ w0, const float* __restrict__ w1,
                                                   const float* __restrict__ w2, const float* __restrict__ w3,
                                                   short* __restrict__ o0, short* __restrict__ o1,
                                                   short* __restrict__ o2, short* __restrict__ o3) {
    const int bid = blockIdx.x;
    const int tid = threadIdx.x;
    if (bid < 4096) {
        int i = (bid * 256 + tid) * 4;
        float4 v = *(const float4*)(x + i);
        short4v o;
        o.x = f2bf(v.x); o.y = f2bf(v.y); o.z = f2bf(v.z); o.w = f2bf(v.w);
        *(short4v*)(xb + i) = o;
        return;
    }
    const int b2 = bid - 4096;
    const int z = b2 >> 10;            // 0..3 which weight
    const int rem = b2 & 1023;
    const int bx = rem & 31, by = rem >> 5;
    const float* src; short* dst;
    switch (z) {
        case 0: src = w0; dst = o0; break;
        case 1: src = w1; dst = o1; break;
        case 2: src = w2; dst = o2; break;
        default: src = w3; dst = o3; break;
    }
    __shared__ float tile[32][33];
    const int tx = tid & 31, ty = tid >> 5;   // 32 x 8
    int c = bx * 32 + tx;
    int r0 = by * 32;
#pragma unroll
    for (int i = 0; i < 4; i++)
        tile[ty + i * 8][tx] = src[(size_t)(r0 + ty + i * 8) * DMODEL + c];
    __syncthreads();
    int co = by * 32 + tx;
    int ro = bx * 32;
#pragma unroll
    for (int i = 0; i < 4; i++)
        dst[(size_t)(ro + ty + i * 8) * DMODEL + co] = f2bf(tile[tx][ty + i * 8]);
}

// ---------------- GEMM v4 (R17/R18-proven): dbuf/prefetch core + XCD-local mapping ----------------
__device__ __forceinline__ void stage_tile(const short* __restrict__ src, int row0, int k0,
                                           short* dstLds, int tid) {
#pragma unroll
    for (int s = 0; s < 4; s++) {
        const int p = s * 4096 + tid * 16;           // linear LDS byte position
        const int q = p ^ (((p >> 7) & 7) << 4);     // inverse-swizzled tile byte
        const char* srcp = (const char*)src + (size_t)(row0 + (q >> 7)) * (DMODEL * 2)
                         + k0 * 2 + (q & 127);
        __builtin_amdgcn_global_load_lds((gas_u32*)srcp,
                                         (las_u32*)((char*)dstLds + p), 16, 0, 0);
    }
}

__device__ __forceinline__ void gemm_core(const short* __restrict__ A,
                                          const short* __restrict__ Bt,
                                          int m0, int n0,
                                          short* Ab0, short* Ab1, short* Bb0, short* Bb1,
                                          floatx4 acc[4][4]) {
    const int tid = threadIdx.x;
    const int lane = tid & 63;
    const int w = tid >> 6;
    const int wr = w >> 1, wc = w & 1;
    const int l15 = lane & 15, lhi = lane >> 4;
    const int swz = (l15 & 7) << 4;

    stage_tile(A, m0, 0, Ab0, tid);
    stage_tile(Bt, n0, 0, Bb0, tid);
    asm volatile("s_waitcnt vmcnt(0)" ::: "memory");
    __syncthreads();

    for (int ks = 0; ks < 16; ks++) {
        const char* Ac = (const char*)((ks & 1) ? Ab1 : Ab0);
        const char* Bc = (const char*)((ks & 1) ? Bb1 : Bb0);
        if (ks < 15) {
            stage_tile(A, m0, (ks + 1) * 64, (ks & 1) ? Ab0 : Ab1, tid);
            stage_tile(Bt, n0, (ks + 1) * 64, (ks & 1) ? Bb0 : Bb1, tid);
        }
#pragma unroll
        for (int kkb = 0; kkb < 128; kkb += 64) {   // byte offset of 32-element K-slice
            short8 af[4], bf[4];
#pragma unroll
            for (int i = 0; i < 4; i++) {
                int row = wr * 64 + i * 16 + l15;
                af[i] = *(const short8*)(Ac + ((row * 128 + kkb + lhi * 16) ^ swz));
            }
#pragma unroll
            for (int j = 0; j < 4; j++) {
                int row = wc * 64 + j * 16 + l15;
                bf[j] = *(const short8*)(Bc + ((row * 128 + kkb + lhi * 16) ^ swz));
            }
#pragma unroll
            for (int i = 0; i < 4; i++)
#pragma unroll
                for (int j = 0; j < 4; j++)
                    acc[i][j] = mfma16(af[i], bf[j], acc[i][j]);
        }
        asm volatile("s_waitcnt vmcnt(0)" ::: "memory");
        __syncthreads();
    }
}

// ---------------- QKV GEMM: 1D grid 768, XCD-local decode ----------------
__global__ __launch_bounds__(256) void gemm_qkv(const short* __restrict__ A,
                                                const short* __restrict__ wq, const short* __restrict__ wk,
                                                const short* __restrict__ wv,
                                                const float* __restrict__ bq, const float* __restrict__ bk,
                                                const float* __restrict__ bv,
                                                short* __restrict__ qh, short* __restrict__ kh,
                                                short* __restrict__ vt) {
    __shared__ __align__(16) short Ab[2][8192];
    __shared__ __align__(16) short Bb[2][8192];
    // decode: xcd(3b) | msub(2b) | n(3b) | mode(2b)
    const int bid = blockIdx.x;
    const int xcd = bid & 7;
    const int slot = bid >> 3;        // 0..95
    const int msub = slot & 3;        // 0..3
    const int c = slot >> 2;          // 0..23
    const int nt = c & 7;             // 0..7
    const int mode = c >> 3;          // 0..2
    const int m0 = (xcd * 4 + msub) * 128;
    const int n0 = nt * 128;

    const short* Bt = (mode == 0) ? wq : (mode == 1) ? wk : wv;
    const float* bias = (mode == 0) ? bq : (mode == 1) ? bk : bv;

    floatx4 acc[4][4];
    floatx4 z = {0.f, 0.f, 0.f, 0.f};
#pragma unroll
    for (int i = 0; i < 4; i++)
#pragma unroll
        for (int j = 0; j < 4; j++) acc[i][j] = z;

    gemm_core(A, Bt, m0, n0, Ab[0], Ab[1], Bb[0], Bb[1], acc);

    const int lane = threadIdx.x & 63;
    const int w = threadIdx.x >> 6;
    const int wr = w >> 1, wc = w & 1;
    const int l15 = lane & 15, lhi = lane >> 4;
    const float qscale = (mode == 0) ? 0.125f : 1.0f;  // fold 1/sqrt(depth) into Q
#pragma unroll
    for (int i = 0; i < 4; i++) {
#pragma unroll
        for (int j = 0; j < 4; j++) {
            int n = n0 + wc * 64 + j * 16 + l15;
            float bv_ = bias[n];
            int h = n >> 6, d = n & 63;
            int mbase = m0 + wr * 64 + i * 16 + (lhi << 2);
#pragma unroll
            for (int r = 0; r < 4; r++) {
                int m = mbase + r;
                int b = m >> 11, s = m & 2047;
                short val = f2bf((acc[i][j][r] + bv_) * qscale);
                if (mode == 0)
                    qh[((size_t)(b * NH + h) * S_LEN + s) * DEPTH + d] = val;
                else if (mode == 1)
                    kh[((size_t)(b * NH + h) * S_LEN + s) * DEPTH + d] = val;
                else
                    vt[((size_t)(b * NH + h) * DEPTH + d) * S_LEN + s] = val;
            }
        }
    }
}

// ---------------- output projection GEMM: 1D grid 256, XCD-local decode ----------------
__global__ __launch_bounds__(256) void gemm_out(const short* __restrict__ A,
                                                const short* __restrict__ Bt,
                                                const float* __restrict__ bias,
                                                float* __restrict__ out) {
    __shared__ __align__(16) short Ab[2][8192];
    __shared__ __align__(16) short Bb[2][8192];
    const int bid = blockIdx.x;
    const int xcd = bid & 7;
    const int slot = bid >> 3;        // 0..31
    const int msub = slot & 3;
    const int nt = slot >> 2;         // 0..7
    const int m0 = (xcd * 4 + msub) * 128;
    const int n0 = nt * 128;

    floatx4 acc[4][4];
    floatx4 z = {0.f, 0.f, 0.f, 0.f};
#pragma unroll
    for (int i = 0; i < 4; i++)
#pragma unroll
        for (int j = 0; j < 4; j++) acc[i][j] = z;

    gemm_core(A, Bt, m0, n0, Ab[0], Ab[1], Bb[0], Bb[1], acc);

    const int lane = threadIdx.x & 63;
    const int w = threadIdx.x >> 6;
    const int wr = w >> 1, wc = w & 1;
    const int l15 = lane & 15, lhi = lane >> 4;
#pragma unroll
    for (int i = 0; i < 4; i++) {
#pragma unroll
        for (int j = 0; j < 4; j++) {
            int n = n0 + wc * 64 + j * 16 + l15;
            float bv_ = bias[n];
            int mbase = m0 + wr * 64 + i * 16 + (lhi << 2);
#pragma unroll
            for (int r = 0; r < 4; r++) {
                int m = mbase + r;
                out[(size_t)m * DMODEL + n] = acc[i][j][r] + bv_;
            }
        }
    }
}

// ---------------- flash attention (R18-proven): defer-max, 64-key tiles ----------------
__constant__ int YCHUNK[16] = {15, 13, 11, 9, 7, 5, 3, 1, 0, 2, 4, 6, 8, 10, 12, 14};

__device__ __forceinline__ void stage_kv(const short* __restrict__ kb_j0,  // kb + j0*DEPTH
                                         const short* __restrict__ vb, int j0,
                                         short* kt, short* vt_, int wid, int lane) {
#pragma unroll
    for (int s = 0; s < 2; s++) {
        const int seg = (s * 4 + wid) * 1024;        // byte segment of the 8KB tile
        const int p = seg + lane * 16;               // linear LDS byte position
        const int q = p ^ (((p >> 7) & 7) << 4);     // inverse-swizzled source offset
        __builtin_amdgcn_global_load_lds((gas_u32*)((const char*)kb_j0 + q),
                                         (las_u32*)((char*)kt + seg), 16, 0, 0);
        const char* vsrc = (const char*)vb + (size_t)(q >> 7) * (S_LEN * 2) + j0 * 2 + (q & 127);
        __builtin_amdgcn_global_load_lds((gas_u32*)vsrc,
                                         (las_u32*)((char*)vt_ + seg), 16, 0, 0);
    }
}

__global__ __launch_bounds__(256, 2) void attn_kernel(const short* __restrict__ qh,
                                                      const short* __restrict__ kh,
                                                      const short* __restrict__ vt,
                                                      const float* __restrict__ pm,
                                                      short* __restrict__ ao) {
    __shared__ short kbuf[2][4096];
    __shared__ short vbuf[2][4096];
    const int lane = threadIdx.x & 63;
    const int wid = threadIdx.x >> 6;  // 0..3
    const int bh = blockIdx.x;         // bh fastest -> same-head blocks share an XCD
    const int chunk = YCHUNK[blockIdx.y];  // complementary pairing across y and y+8
    const int b = bh >> 4, h = bh & 15;
    const short* qbp = qh + (size_t)bh * S_LEN * DEPTH;
    const short* kb = kh + (size_t)bh * S_LEN * DEPTH;
    const short* vb = vt + (size_t)bh * DEPTH * S_LEN;
    const float* pmb = pm + b * S_LEN;
    const int l15 = lane & 15, lhi = lane >> 4;
    const int swz = (l15 & 7) << 4;

    const int qwb = chunk * 128 + wid * 32;

    short8 qf[2][2];
#pragma unroll
    for (int qg = 0; qg < 2; qg++)
#pragma unroll
        for (int c = 0; c < 2; c++)
            qf[qg][c] = *(const short8*)(qbp + (size_t)(qwb + qg * 16 + l15) * DEPTH + c * 32 + lhi * 8);

    float m_r[2] = {-1e30f, -1e30f};
    float l_part[2] = {0.f, 0.f};
    floatx4 oacc[2][4];
    floatx4 z = {0.f, 0.f, 0.f, 0.f};
#pragma unroll
    for (int qg = 0; qg < 2; qg++)
#pragma unroll
        for (int dt = 0; dt < 4; dt++) oacc[qg][dt] = z;

    const int NT = 2 * chunk + 2;  // key tiles 0 .. chunk*128+64
    stage_kv(kb, vb, 0, kbuf[0], vbuf[0], wid, lane);
    __syncthreads();

    for (int t = 0; t < NT; t++) {
        const int cur = t & 1;
        if (t + 1 < NT)
            stage_kv(kb + (size_t)(t + 1) * 64 * DEPTH, vb, (t + 1) * 64,
                     kbuf[cur ^ 1], vbuf[cur ^ 1], wid, lane);
        const int j0 = t * 64;
        if (j0 <= qwb + 31) {  // wave-uniform: skip fully-masked tiles (barriers still hit)
            const short* kt = kbuf[cur];
            const short* vtile = vbuf[cur];
            short8 kf[4][2];
#pragma unroll
            for (int tt = 0; tt < 4; tt++)
#pragma unroll
                for (int c = 0; c < 2; c++) {
                    int off = (((tt * 16 + l15) * 128) + c * 64 + lhi * 16) ^ swz;
                    kf[tt][c] = *(const short8*)((const char*)kt + off);
                }
            floatx4 sacc[2][4];
#pragma unroll
            for (int qg = 0; qg < 2; qg++)
#pragma unroll
                for (int tt = 0; tt < 4; tt++) sacc[qg][tt] = z;
#pragma unroll
            for (int tt = 0; tt < 4; tt++)
#pragma unroll
                for (int c = 0; c < 2; c++) {
                    sacc[0][tt] = mfma16(kf[tt][c], qf[0][c], sacc[0][tt]);
                    sacc[1][tt] = mfma16(kf[tt][c], qf[1][c], sacc[1][tt]);
                }
            short4v vf[4][4];
#pragma unroll
            for (int tt = 0; tt < 4; tt++)
#pragma unroll
                for (int dt = 0; dt < 4; dt++) {
                    int off = (((dt * 16 + l15) * 128) + tt * 32 + lhi * 8) ^ swz;
                    vf[tt][dt] = *(const short4v*)((const char*)vtile + off);
                }
            float pd[16];
#pragma unroll
            for (int tt = 0; tt < 4; tt++) {
                float4 pmv = *(const float4*)(pmb + j0 + tt * 16 + lhi * 4);
                pd[tt * 4 + 0] = (1.f - pmv.x) * -1e9f;
                pd[tt * 4 + 1] = (1.f - pmv.y) * -1e9f;
                pd[tt * 4 + 2] = (1.f - pmv.z) * -1e9f;
                pd[tt * 4 + 3] = (1.f - pmv.w) * -1e9f;
            }
#pragma unroll
            for (int qg = 0; qg < 2; qg++) {
                const int q = qwb + qg * 16 + l15;
                const bool domask = (j0 + 63 > qwb + qg * 16);
                float mx = -1e30f;
#pragma unroll
                for (int tt = 0; tt < 4; tt++)
#pragma unroll
                    for (int r = 0; r < 4; r++) {
                        float v = sacc[qg][tt][r] + pd[tt * 4 + r];
                        if (domask) {
                            int key = j0 + tt * 16 + lhi * 4 + r;
                            v = (key > q) ? -1e30f : v;
                        }
                        sacc[qg][tt][r] = v;
                        mx = fmaxf(mx, v);
                    }
                // T13 defer-max: rescale only when the row max materially grows.
                if (!__all(mx <= m_r[qg] + 12.0f)) {
                    mx = fmaxf(mx, __shfl_xor(mx, 16, 64));
                    mx = fmaxf(mx, __shfl_xor(mx, 32, 64));
                    float mnew = fmaxf(m_r[qg], mx);
                    float sf = __expf(m_r[qg] - mnew);
                    m_r[qg] = mnew;
                    l_part[qg] *= sf;
#pragma unroll
                    for (int r = 0; r < 4; r++) {
                        float sfr = __shfl(sf, lhi * 4 + r, 64);
#pragma unroll
                        for (int dt = 0; dt < 4; dt++) oacc[qg][dt][r] *= sfr;
                    }
                }
#pragma unroll
                for (int tt = 0; tt < 4; tt++) {
                    float p0 = __expf(sacc[qg][tt][0] - m_r[qg]);
                    float p1 = __expf(sacc[qg][tt][1] - m_r[qg]);
                    float p2 = __expf(sacc[qg][tt][2] - m_r[qg]);
                    float p3 = __expf(sacc[qg][tt][3] - m_r[qg]);
                    l_part[qg] += (p0 + p1) + (p2 + p3);
                    union { unsigned u[2]; short4v s; } cv;
                    cv.u[0] = packbf2(p0, p1);
                    cv.u[1] = packbf2(p2, p3);
#pragma unroll
                    for (int dt = 0; dt < 4; dt++)
                        oacc[qg][dt] = mfma16k16(cv.s, vf[tt][dt], oacc[qg][dt]);
                }
            }
        }
        asm volatile("s_waitcnt vmcnt(0)" ::: "memory");
        __syncthreads();
    }

    // ---- epilogue: reduce per-lane partial sums once ----
#pragma unroll
    for (int qg = 0; qg < 2; qg++) {
        float lsum = l_part[qg];
        lsum += __shfl_xor(lsum, 16, 64);
        lsum += __shfl_xor(lsum, 32, 64);
        float rinv[4];
#pragma unroll
        for (int r = 0; r < 4; r++)
            rinv[r] = 1.0f / __shfl(lsum, lhi * 4 + r, 64);
#pragma unroll
        for (int dt = 0; dt < 4; dt++) {
            int d = dt * 16 + l15;
#pragma unroll
            for (int r = 0; r < 4; r++) {
                int row = qwb + qg * 16 + lhi * 4 + r;
                float o = oacc[qg][dt][r] * rinv[r];
                ao[((size_t)(b * S_LEN) + row) * DMODEL + h * DEPTH + d] = f2bf(o);
            }
        }
    }
}

extern "C" void kernel_launch(void* const* d_in, const int* in_sizes, int n_in,
                              void* d_out, int out_size, void* d_ws, size_t ws_size,
                              hipStream_t stream) {
    const float* x    = (const float*)d_in[0];
    const float* pm   = (const float*)d_in[1];
    const float* wq_w = (const float*)d_in[2];
    const float* wq_b = (const float*)d_in[3];
    const float* wk_w = (const float*)d_in[4];
    const float* wk_b = (const float*)d_in[5];
    const float* wv_w = (const float*)d_in[6];
    const float* wv_b = (const float*)d_in[7];
    const float* wo_w = (const float*)d_in[8];
    const float* wo_b = (const float*)d_in[9];
    float* out = (float*)d_out;

    char* ws = (char*)d_ws;
    const size_t MB = 1024 * 1024;
    short* xb  = (short*)(ws);            // 8 MB : x bf16 (4096x1024)
    short* wqb = (short*)(ws + 8 * MB);   // 2 MB : wq^T bf16
    short* wkb = (short*)(ws + 10 * MB);
    short* wvb = (short*)(ws + 12 * MB);
    short* wob = (short*)(ws + 14 * MB);
    short* qh  = (short*)(ws + 16 * MB);  // 8 MB : Q (B,H,S,depth) bf16, pre-scaled by 0.125
    short* kh  = (short*)(ws + 24 * MB);  // 8 MB : K (B,H,S,depth) bf16
    short* vt  = (short*)(ws + 32 * MB);  // 8 MB : V^T (B,H,depth,S) bf16
    short* ao  = (short*)(ws + 40 * MB);  // 8 MB : attn out (B,S,D) bf16

    prep_kernel<<<8192, 256, 0, stream>>>(x, xb, wq_w, wk_w, wv_w, wo_w,
                                          wqb, wkb, wvb, wob);
    gemm_qkv<<<768, 256, 0, stream>>>(xb, wqb, wkb, wvb, wq_b, wk_b, wv_b,
                                      qh, kh, vt);
    attn_kernel<<<dim3(32, 16), 256, 0, stream>>>(qh, kh, vt, pm, ao);
    gemm_out<<<256, 256, 0, stream>>>(ao, wob, wo_b, out);
}